// Round 9
// baseline (5940.588 us; speedup 1.0000x reference)
//
#include <hip/hip_runtime.h>
#include <cstdint>

typedef unsigned short u16;
typedef unsigned int   u32;
typedef __bf16 v8bf  __attribute__((ext_vector_type(8)));
typedef float  v4f   __attribute__((ext_vector_type(4)));
typedef u32    u32x2 __attribute__((ext_vector_type(2)));
typedef u32    u32x4 __attribute__((ext_vector_type(4)));

#define T_STEPS 1024
#define G3 1536

// ws layout (bytes). Rings overlap the head of xbf (dead after k_gemm; memset
// is issued after k_gemm, before k_lstm).
#define OFF_RING0 0ull          // L0 h/c ring [4 slots][4 grp][16 rows][512] 8B = 1,048,576
#define OFF_RING1 1048576ull    // L1 h/c ring, same shape = 1,048,576
#define OFF_XBF   0ull          // x bf16 [65536,512] 67,108,864 (dead after gemm)
#define OFF_XG    67108864ull   // xg0 bf16 [65536,1536] 201,326,592
#define OFF_WII   268435456ull  // Wii layer0 bf16 [1536,512] 1,572,864
#define OFF_WPACK 270008320ull  // packed recurrent B-frags (2 layers) 7,340,032
#define OFF_WPK2  277348352ull  // packed Wii layer1 B-frags 1,572,864
#define OFF_BIASF 278921216ull  // folded gate bias f32 [2,1536] 12,288

__device__ __forceinline__ u16 f2b(float f) {
  u32 u = __builtin_bit_cast(u32, f);
  u += 0x7fffu + ((u >> 16) & 1u);
  return (u16)(u >> 16);
}
__device__ __forceinline__ float b2f(u16 h) {
  u32 u = ((u32)h) << 16;
  return __builtin_bit_cast(float, u);
}
__device__ __forceinline__ float sigm(float x) { return 1.0f / (1.0f + __expf(-x)); }

// ---------------- prep kernels ----------------

__global__ void k_cvt(const float* __restrict__ s, u16* __restrict__ d, int n4) {
  int i = blockIdx.x * blockDim.x + threadIdx.x;
  int st = gridDim.x * blockDim.x;
  for (; i < n4; i += st) {
    float4 v = reinterpret_cast<const float4*>(s)[i];
    u32 lo = (u32)f2b(v.x) | ((u32)f2b(v.y) << 16);
    u32 hi = (u32)f2b(v.z) | ((u32)f2b(v.w) << 16);
    uint2 pk; pk.x = lo; pk.y = hi;
    reinterpret_cast<uint2*>(d)[i] = pk;
  }
}

__global__ void k_fold(const float* __restrict__ a, const float* __restrict__ b,
                       const float* __restrict__ c, float* __restrict__ o, int n) {
  int i = blockIdx.x * blockDim.x + threadIdx.x;
  if (i < n) o[i] = a[i] + b[i] + c[i];
}

// Recurrent weights -> MFMA B-frag order (both layers). [l][s][112][64][8]:
// c<96: gates tau=c>>5, kk=c&31 (K=1024: k<512 Wih, k>=512 Wic); c>=96: Whh.
__global__ void k_pack(const float* __restrict__ Wih, const float* __restrict__ Wic,
                       const float* __restrict__ Whh, u16* __restrict__ wp) {
  int t = blockIdx.x * blockDim.x + threadIdx.x;
  if (t >= 2 * 32 * 112 * 64) return;
  int lane = t & 63; int rest = t >> 6;
  int c = rest % 112; rest /= 112;
  int s = rest & 31; int l = rest >> 5;
  int col16 = lane & 15, kq = lane >> 4;
  const float* src;
  if (c < 96) {
    int tau = c >> 5, kk = c & 31;
    int col = tau * 512 + s * 16 + col16;
    int k = kk * 32 + kq * 8;
    src = (k < 512) ? (Wih + ((size_t)l * G3 + col) * 512 + k)
                    : (Wic + ((size_t)l * G3 + col) * 512 + (k - 512));
  } else {
    int kk = c - 96;
    int col = s * 16 + col16;
    int k = kk * 32 + kq * 8;
    src = Whh + ((size_t)l * 512 + col) * 512 + k;
  }
  u16 o[8];
#pragma unroll
  for (int i = 0; i < 8; ++i) o[i] = f2b(src[i]);
  uint4 v;
  v.x = (u32)o[0] | ((u32)o[1] << 16);
  v.y = (u32)o[2] | ((u32)o[3] << 16);
  v.z = (u32)o[4] | ((u32)o[5] << 16);
  v.w = (u32)o[6] | ((u32)o[7] << 16);
  reinterpret_cast<uint4*>(wp)[t] = v;
}

// Wii layer-1 -> B-frag order. [s][wg(3)][kk(16)][lane(64)][8]; B[k][col]=Wii1[col][k].
__global__ void k_pack2(const float* __restrict__ Wii, u16* __restrict__ wp2) {
  int t = blockIdx.x * blockDim.x + threadIdx.x;
  if (t >= 32 * 3 * 16 * 64) return;
  int lane = t & 63;
  int kk = (t >> 6) & 15;
  int w = (t >> 10) % 3;
  int s = t / 3072;
  int col = w * 512 + s * 16 + (lane & 15);
  int k = kk * 32 + (lane >> 4) * 8;
  const float* src = Wii + ((size_t)G3 + col) * 512 + k;   // layer-1 slice
  u16 o[8];
#pragma unroll
  for (int i = 0; i < 8; ++i) o[i] = f2b(src[i]);
  uint4 v;
  v.x = (u32)o[0] | ((u32)o[1] << 16);
  v.y = (u32)o[2] | ((u32)o[3] << 16);
  v.z = (u32)o[4] | ((u32)o[5] << 16);
  v.w = (u32)o[6] | ((u32)o[7] << 16);
  reinterpret_cast<uint4*>(wp2)[t] = v;
}

// ---------------- xg0 GEMM: C[M,1536] = A[M,512] * Bt[1536,512]^T ----------------

__global__ __launch_bounds__(256) void k_gemm(const u16* __restrict__ A,
                                              const u16* __restrict__ Bt,
                                              u16* __restrict__ C) {
  __shared__ u16 As[128 * 40];
  __shared__ u16 Bs[128 * 40];
  int m0 = blockIdx.x * 128, n0 = blockIdx.y * 128;
  int tid = threadIdx.x, lane = tid & 63, w = tid >> 6, wr = w >> 1, wc = w & 1;
  int rl = lane & 15, kq = lane >> 4;
  v4f acc[4][4] = {};
  for (int k0 = 0; k0 < 512; k0 += 32) {
#pragma unroll
    for (int c = tid; c < 1024; c += 256) {
      int row = (c & 511) >> 2, q = c & 3;
      const u16* src = (c < 512) ? (A + (size_t)(m0 + row) * 512 + k0 + q * 8)
                                 : (Bt + (size_t)(n0 + row) * 512 + k0 + q * 8);
      uint4 v = *reinterpret_cast<const uint4*>(src);
      u16* dst = (c < 512) ? (As + row * 40 + q * 8) : (Bs + row * 40 + q * 8);
      *reinterpret_cast<uint4*>(dst) = v;
    }
    __syncthreads();
    v8bf a[4], b[4];
#pragma unroll
    for (int mi = 0; mi < 4; ++mi)
      a[mi] = *reinterpret_cast<const v8bf*>(As + (wr * 64 + mi * 16 + rl) * 40 + kq * 8);
#pragma unroll
    for (int ni = 0; ni < 4; ++ni)
      b[ni] = *reinterpret_cast<const v8bf*>(Bs + (wc * 64 + ni * 16 + rl) * 40 + kq * 8);
#pragma unroll
    for (int mi = 0; mi < 4; ++mi)
#pragma unroll
      for (int ni = 0; ni < 4; ++ni)
        acc[mi][ni] = __builtin_amdgcn_mfma_f32_16x16x32_bf16(a[mi], b[ni], acc[mi][ni], 0, 0, 0);
    __syncthreads();
  }
#pragma unroll
  for (int mi = 0; mi < 4; ++mi)
#pragma unroll
    for (int ni = 0; ni < 4; ++ni)
#pragma unroll
      for (int r = 0; r < 4; ++r) {
        int row = m0 + wr * 64 + mi * 16 + kq * 4 + r;
        int col = n0 + wc * 64 + ni * 16 + rl;
        C[(size_t)row * G3 + col] = f2b(acc[mi][ni][r]);
      }
}

// ---------------- persistent 2-layer role-split recurrence ----------------
// 128 blocks x 512 threads. Waves 0-3 = layer 0 (gate i,f,o + cell), waves 4-7
// = layer 1 (same roles, + folded x1@Wii1). At iter t: L0 computes pos t, L1
// computes pos t-1 CONCURRENTLY (inputs for both are ready after the combined
// ring stage). Per-role sync via LDS-counter sub-barriers (4 waves each); only
// 2 full __syncthreads per iter (stage-done, iter-end WAR).
// Sync protocol (R3/R8-proven): tagged 8B packets {h|c<<16, tag} via sc0 sc1,
// depth-4 rings; both rings polled in ONE combined spin (per-chunk retry).

__global__ __launch_bounds__(512, 1) void k_lstm(
    const u16* __restrict__ xg, const u16* __restrict__ wp, const u16* __restrict__ wp2,
    const float* __restrict__ biasf, const float* __restrict__ bhh,
    const float* __restrict__ xin, float* __restrict__ outs,
    float* __restrict__ hn, float* __restrict__ cn,
    char* __restrict__ ring0, char* __restrict__ ring1) {
  extern __shared__ char lds[];
  u16* alds   = (u16*)lds;                 // 16 rows x 2056 u16: [h0|c0|h1|c1]+pad
  float* olds = (float*)(lds + 65792);     // [0..1023] L0 gate tiles, [1024..2047] L1
  u16* w1lds  = (u16*)(lds + 73984);       // Wii1 B-frags: [wg(3)][kk(16)][lane][8]
  u32* scnt   = (u32*)(lds + 123136);      // [0]=L0 subbar counter, [1]=L1
  int tid = threadIdx.x, lane = tid & 63, w = tid >> 6;
  bool isL1 = w >= 4;
  int wg = w & 3;                          // 0,1,2 = gate i/f/o ; 3 = cellgate
  int blk = blockIdx.x, g = blk >> 5, s = blk & 31;

  int et = tid & 255;                      // elementwise ownership within role
  int erow = et >> 4, ecol = et & 15;
  int bglob = g * 16 + erow, hcol = s * 16 + ecol;
  int col16 = lane & 15, kq = lane >> 4;
  bool isGate = (wg < 3);
  float bias_w;
  int cbase, nfr;
  if (isGate) {
    cbase = wg * 32; nfr = 32;
    bias_w = biasf[(isL1 ? 1536 : 0) + wg * 512 + s * 16 + col16];
  } else {
    cbase = 96; nfr = 16;
    bias_w = bhh[(isL1 ? 512 : 0) + s * 16 + col16];
  }
  int colglob = wg * 512 + s * 16 + col16;

  // one-time: this wave's layer's recurrent B-frags -> registers
  const u16* wsrc = wp + (isL1 ? 1835008u : 0u) + (size_t)s * 57344
                    + (size_t)cbase * 512 + lane * 8;
  v8bf breg[32];
#pragma unroll
  for (int kk = 0; kk < 32; ++kk)
    if (kk < nfr) breg[kk] = *reinterpret_cast<const v8bf*>(wsrc + kk * 512);
  // one-time: Wii1 B-frag slice -> LDS (48KB)
  {
    const uint4* src = reinterpret_cast<const uint4*>(wp2) + (size_t)s * 3072;
    for (int i = tid; i < 3072; i += 512)
      reinterpret_cast<uint4*>(w1lds)[i] = src[i];
  }
  if (tid < 2) scnt[tid] = 0;
  float c_st = 0.0f;                       // c0 for tid<256 owners, c1 for tid>=256
  __syncthreads();

  auto Af = [&](int base, int kg) {
    return *reinterpret_cast<const v8bf*>(alds + col16 * 2056 + base + kg * 32 + kq * 8);
  };

  for (int t = 0; t <= T_STEPS; ++t) {
    bool doL0 = (t < T_STEPS), doL1 = (t > 0);

    // ---- prefetch read-only data (plain cached loads) ----
    float seed[4] = {0.f, 0.f, 0.f, 0.f};
    float xi0 = 0.0f;
    if (!isL1 && doL0) {
      if (isGate) {
        const u16* xgp = xg + (size_t)(t * 64 + g * 16 + kq * 4) * G3 + colglob;
#pragma unroll
        for (int r4 = 0; r4 < 4; ++r4) seed[r4] = b2f(xgp[(size_t)r4 * G3]) + bias_w;
      } else {
#pragma unroll
        for (int r4 = 0; r4 < 4; ++r4) seed[r4] = bias_w;
      }
      if (tid < 256) xi0 = xin[(size_t)(t * 64 + bglob) * 512 + hcol];
    }

    // ---- combined poll of both rings: 16 loads in flight, one drain ----
    u32x4 r0[8], r1[8];
    {
      const char* pb0 = ring0 + ((size_t)(t & 3) * 4 + g) * 65536 + (size_t)tid * 16;
      const char* pb1 = ring1 + ((size_t)((t - 1) & 3) * 4 + g) * 65536 + (size_t)tid * 16;
      u32 exp0 = (u32)t, exp1 = (u32)(t - 1);
      u32 m0 = 0xffu, m1 = doL1 ? 0xffu : 0u;
      u32 it = 0;
      for (;;) {
#pragma unroll
        for (int i = 0; i < 8; ++i) if ((m0 >> i) & 1)
          asm volatile("global_load_dwordx4 %0, %1, off sc0 sc1"
                       : "=v"(r0[i]) : "v"(pb0 + (size_t)i * 8192) : "memory");
#pragma unroll
        for (int i = 0; i < 8; ++i) if ((m1 >> i) & 1)
          asm volatile("global_load_dwordx4 %0, %1, off sc0 sc1"
                       : "=v"(r1[i]) : "v"(pb1 + (size_t)i * 8192) : "memory");
        asm volatile("s_waitcnt vmcnt(0)" ::: "memory");
        __builtin_amdgcn_sched_barrier(0);
#pragma unroll
        for (int i = 0; i < 8; ++i)
          if ((r0[i][1] == exp0) && (r0[i][3] == exp0)) m0 &= ~(1u << i);
#pragma unroll
        for (int i = 0; i < 8; ++i)
          if ((r1[i][1] == exp1) && (r1[i][3] == exp1)) m1 &= ~(1u << i);
        if (!(m0 | m1)) break;
        if (++it > (1u << 11)) break;
        __builtin_amdgcn_s_sleep(1);
      }
      __builtin_amdgcn_sched_barrier(0);
      // unpack: h0 -> [0,512), c0 -> [512,1024), h1 -> [1024,1536), c1 -> [1536,2048)
#pragma unroll
      for (int i = 0; i < 8; ++i) {
        int p = tid + i * 512;
        int row = p >> 8, c2 = p & 255;
        u32 hw = (r0[i][0] & 0xffffu) | (r0[i][2] << 16);
        u32 cw = (r0[i][0] >> 16) | (r0[i][2] & 0xffff0000u);
        *reinterpret_cast<u32*>(alds + row * 2056 + 2 * c2) = hw;
        *reinterpret_cast<u32*>(alds + row * 2056 + 512 + 2 * c2) = cw;
      }
      if (doL1) {
#pragma unroll
        for (int i = 0; i < 8; ++i) {
          int p = tid + i * 512;
          int row = p >> 8, c2 = p & 255;
          u32 hw = (r1[i][0] & 0xffffu) | (r1[i][2] << 16);
          u32 cw = (r1[i][0] >> 16) | (r1[i][2] & 0xffff0000u);
          *reinterpret_cast<u32*>(alds + row * 2056 + 1024 + 2 * c2) = hw;
          *reinterpret_cast<u32*>(alds + row * 2056 + 1536 + 2 * c2) = cw;
        }
      }
    }
    __syncthreads();   // S1: both rings staged

    if (!isL1) {
      // =========================== LAYER 0: position t ===========================
      if (doL0) {
        v4f ac0, ac1, ac2, ac3;
#pragma unroll
        for (int r4 = 0; r4 < 4; ++r4) { ac0[r4] = seed[r4]; ac1[r4] = 0.f; ac2[r4] = 0.f; ac3[r4] = 0.f; }
        if (isGate) {
#pragma unroll
          for (int kk = 0; kk < 32; kk += 4) {
            ac0 = __builtin_amdgcn_mfma_f32_16x16x32_bf16(Af(0, kk + 0), breg[kk + 0], ac0, 0, 0, 0);
            ac1 = __builtin_amdgcn_mfma_f32_16x16x32_bf16(Af(0, kk + 1), breg[kk + 1], ac1, 0, 0, 0);
            ac2 = __builtin_amdgcn_mfma_f32_16x16x32_bf16(Af(0, kk + 2), breg[kk + 2], ac2, 0, 0, 0);
            ac3 = __builtin_amdgcn_mfma_f32_16x16x32_bf16(Af(0, kk + 3), breg[kk + 3], ac3, 0, 0, 0);
          }
        } else {
#pragma unroll
          for (int kk = 0; kk < 16; kk += 4) {
            ac0 = __builtin_amdgcn_mfma_f32_16x16x32_bf16(Af(0, kk + 0), breg[kk + 0], ac0, 0, 0, 0);
            ac1 = __builtin_amdgcn_mfma_f32_16x16x32_bf16(Af(0, kk + 1), breg[kk + 1], ac1, 0, 0, 0);
            ac2 = __builtin_amdgcn_mfma_f32_16x16x32_bf16(Af(0, kk + 2), breg[kk + 2], ac2, 0, 0, 0);
            ac3 = __builtin_amdgcn_mfma_f32_16x16x32_bf16(Af(0, kk + 3), breg[kk + 3], ac3, 0, 0, 0);
          }
        }
        v4f acc;
#pragma unroll
        for (int r4 = 0; r4 < 4; ++r4) acc[r4] = (ac0[r4] + ac1[r4]) + (ac2[r4] + ac3[r4]);
#pragma unroll
        for (int r4 = 0; r4 < 4; ++r4) olds[wg * 256 + (kq * 4 + r4) * 16 + col16] = acc[r4];
        // sub-barrier: waves 0-3 only
        asm volatile("s_waitcnt lgkmcnt(0)" ::: "memory");
        if (lane == 0) atomicAdd(&scnt[0], 1u);
        {
          volatile u32* vc = &scnt[0];
          u32 tgt = 4u * (u32)(t + 1);
          while (*vc < tgt) {}
        }
        __builtin_amdgcn_sched_barrier(0);

        float gi = olds[et], gf = olds[256 + et], go = olds[512 + et], gg = olds[768 + et];
        float i_s = sigm(gi), f_s = sigm(gf), o_s = sigm(go);
        float cg = tanhf(gg);
        float cy = f_s * c_st + i_s * cg;
        float hy = o_s * (tanhf(cy) + xi0);
        c_st = cy;
        u16 hyb = f2b(hy), cyb = f2b(cy);
        u32x2 pkt;
        pkt[0] = (u32)hyb | ((u32)cyb << 16);
        pkt[1] = (u32)(t + 1);
        void* pd = ring0 + ((size_t)((t + 1) & 3) * 4 + g) * 65536
                   + (size_t)(erow * 512 + hcol) * 8;
        asm volatile("global_store_dwordx2 %0, %1, off sc0 sc1"
                     :: "v"(pd), "v"(pkt) : "memory");
        if (t == T_STEPS - 1) {
          hn[bglob * 512 + hcol] = hy;
          cn[bglob * 512 + hcol] = cy;
        }
      }
    } else {
      // ========================= LAYER 1: position t-1 =========================
      if (doL1) {
        float xi1 = b2f(alds[erow * 2056 + hcol]);   // h0 tag t = L0 out pos t-1
        v4f ac0, ac1, ac2, ac3;
#pragma unroll
        for (int r4 = 0; r4 < 4; ++r4) { ac0[r4] = bias_w; ac1[r4] = 0.f; ac2[r4] = 0.f; ac3[r4] = 0.f; }
        if (isGate) {
#pragma unroll
          for (int kk = 0; kk < 32; kk += 4) {       // h1|c1 recurrent, K=1024
            ac0 = __builtin_amdgcn_mfma_f32_16x16x32_bf16(Af(1024, kk + 0), breg[kk + 0], ac0, 0, 0, 0);
            ac1 = __builtin_amdgcn_mfma_f32_16x16x32_bf16(Af(1024, kk + 1), breg[kk + 1], ac1, 0, 0, 0);
            ac2 = __builtin_amdgcn_mfma_f32_16x16x32_bf16(Af(1024, kk + 2), breg[kk + 2], ac2, 0, 0, 0);
            ac3 = __builtin_amdgcn_mfma_f32_16x16x32_bf16(Af(1024, kk + 3), breg[kk + 3], ac3, 0, 0, 0);
          }
#pragma unroll
          for (int kx = 0; kx < 16; kx += 4) {       // x1 @ Wii1, K=512, B from LDS
            ac0 = __builtin_amdgcn_mfma_f32_16x16x32_bf16(Af(0, kx + 0),
                    *reinterpret_cast<const v8bf*>(w1lds + ((wg * 16 + kx + 0) * 64 + lane) * 8), ac0, 0, 0, 0);
            ac1 = __builtin_amdgcn_mfma_f32_16x16x32_bf16(Af(0, kx + 1),
                    *reinterpret_cast<const v8bf*>(w1lds + ((wg * 16 + kx + 1) * 64 + lane) * 8), ac1, 0, 0, 0);
            ac2 = __builtin_amdgcn_mfma_f32_16x16x32_bf16(Af(0, kx + 2),
                    *reinterpret_cast<const v8bf*>(w1lds + ((wg * 16 + kx + 2) * 64 + lane) * 8), ac2, 0, 0, 0);
            ac3 = __builtin_amdgcn_mfma_f32_16x16x32_bf16(Af(0, kx + 3),
                    *reinterpret_cast<const v8bf*>(w1lds + ((wg * 16 + kx + 3) * 64 + lane) * 8), ac3, 0, 0, 0);
          }
        } else {
#pragma unroll
          for (int kk = 0; kk < 16; kk += 4) {       // cell: h1 only, K=512
            ac0 = __builtin_amdgcn_mfma_f32_16x16x32_bf16(Af(1024, kk + 0), breg[kk + 0], ac0, 0, 0, 0);
            ac1 = __builtin_amdgcn_mfma_f32_16x16x32_bf16(Af(1024, kk + 1), breg[kk + 1], ac1, 0, 0, 0);
            ac2 = __builtin_amdgcn_mfma_f32_16x16x32_bf16(Af(1024, kk + 2), breg[kk + 2], ac2, 0, 0, 0);
            ac3 = __builtin_amdgcn_mfma_f32_16x16x32_bf16(Af(1024, kk + 3), breg[kk + 3], ac3, 0, 0, 0);
          }
        }
        v4f acc;
#pragma unroll
        for (int r4 = 0; r4 < 4; ++r4) acc[r4] = (ac0[r4] + ac1[r4]) + (ac2[r4] + ac3[r4]);
#pragma unroll
        for (int r4 = 0; r4 < 4; ++r4) olds[1024 + wg * 256 + (kq * 4 + r4) * 16 + col16] = acc[r4];
        // sub-barrier: waves 4-7 only
        asm volatile("s_waitcnt lgkmcnt(0)" ::: "memory");
        if (lane == 0) atomicAdd(&scnt[1], 1u);
        {
          volatile u32* vc = &scnt[1];
          u32 tgt = 4u * (u32)t;
          while (*vc < tgt) {}
        }
        __builtin_amdgcn_sched_barrier(0);

        float gi = olds[1024 + et], gf = olds[1280 + et], go = olds[1536 + et], gg = olds[1792 + et];
        float i_s = sigm(gi), f_s = sigm(gf), o_s = sigm(go);
        float cg = tanhf(gg);
        float cy = f_s * c_st + i_s * cg;
        float hy = o_s * (tanhf(cy) + xi1);
        c_st = cy;
        u16 hyb = f2b(hy), cyb = f2b(cy);
        u32x2 pkt;
        pkt[0] = (u32)hyb | ((u32)cyb << 16);
        pkt[1] = (u32)t;
        void* pd = ring1 + ((size_t)(t & 3) * 4 + g) * 65536
                   + (size_t)(erow * 512 + hcol) * 8;
        asm volatile("global_store_dwordx2 %0, %1, off sc0 sc1"
                     :: "v"(pd), "v"(pkt) : "memory");
        outs[(size_t)((t - 1) * 64 + bglob) * 512 + hcol] = hy;
        if (t == T_STEPS) {
          hn[32768 + bglob * 512 + hcol] = hy;
          cn[32768 + bglob * 512 + hcol] = cy;
        }
      }
    }
    __syncthreads(); // S2: all alds/olds reads done before next iter's writes
  }
}

// ---------------- launch ----------------

extern "C" void kernel_launch(void* const* d_in, const int* in_sizes, int n_in,
                              void* d_out, int out_size, void* d_ws, size_t ws_size,
                              hipStream_t stream) {
  const float* x   = (const float*)d_in[0];
  const float* Wii = (const float*)d_in[1];
  const float* Wic = (const float*)d_in[2];
  const float* Wih = (const float*)d_in[3];
  const float* bii = (const float*)d_in[4];
  const float* bic = (const float*)d_in[5];
  const float* bih = (const float*)d_in[6];
  const float* Whh = (const float*)d_in[7];
  const float* bhh = (const float*)d_in[8];
  float* out = (float*)d_out;
  char* ws = (char*)d_ws;

  u16* xbf     = (u16*)(ws + OFF_XBF);
  u16* xgb     = (u16*)(ws + OFF_XG);
  u16* wiib    = (u16*)(ws + OFF_WII);
  u16* wpack   = (u16*)(ws + OFF_WPACK);
  u16* wpk2    = (u16*)(ws + OFF_WPK2);
  float* biasf = (float*)(ws + OFF_BIASF);

  hipFuncSetAttribute(reinterpret_cast<const void*>(k_lstm),
                      hipFuncAttributeMaxDynamicSharedMemorySize, 123152);

  // prep
  k_cvt <<<2048, 256, 0, stream>>>(x, xbf, 8388608);
  k_cvt <<<768, 256, 0, stream>>>(Wii, wiib, 196608);          // layer-0 Wii only
  k_fold<<<12, 256, 0, stream>>>(bii, bic, bih, biasf, 3072);
  k_pack<<<1792, 256, 0, stream>>>(Wih, Wic, Whh, wpack);
  k_pack2<<<384, 256, 0, stream>>>(Wii, wpk2);
  k_gemm<<<dim3(512, 12), 256, 0, stream>>>(xbf, wiib, xgb);   // xg0 only

  // rings overlap head of xbf: clear AFTER k_gemm consumed it.
  hipMemsetAsync(ws + OFF_RING0, 0, 2097152, stream);

  float* hn = out + 33554432;
  float* cn = out + 33554432 + 65536;
  k_lstm<<<128, 512, 123152, stream>>>(
      xgb, wpack, wpk2, biasf, bhh, x, out, hn, cn,
      ws + OFF_RING0, ws + OFF_RING1);
}